// Round 1
// baseline (524.554 us; speedup 1.0000x reference)
//
#include <hip/hip_runtime.h>
#include <hip/hip_bf16.h>
#include <cstdint>

// Problem constants
#define Bk 32
#define Sk 256
#define Wk 32
#define Tk 16
#define Ek 300
#define Hk 128
#define Dk 128
#define NROWS (Bk*Sk)          // 8192
#define GI_N  (3*Hk*2)         // 768

// ---------------- helpers ----------------
__device__ __forceinline__ float fast_sigmoid(float x) {
    return 1.f / (1.f + __expf(-x));
}
__device__ __forceinline__ float fast_tanh(float x) {
    float ax = fabsf(x);
    float e = __expf(2.f * ax);
    float t = 1.f - 2.f / (1.f + e);
    return copysignf(t, x);
}

// ---------------- pack kernel ----------------
// Bgi[k][n] (300x768): n<384 -> Wih_f[n][k], else Wih_b[n-384][k]
// bias_gi[768] = concat(bih_f, bih_b)
// BW1[k][n] (512x128) = W1[n][k]
__global__ __launch_bounds__(256) void pack_kernel(
    const float* __restrict__ Wf, const float* __restrict__ Wb,
    const float* __restrict__ bf, const float* __restrict__ bb,
    const float* __restrict__ W1,
    float* __restrict__ Bgi, float* __restrict__ bias_gi, float* __restrict__ BW1)
{
    int idx = blockIdx.x * 256 + threadIdx.x;
    if (idx < 300 * 768) {
        int k = idx / 768, n = idx % 768;
        Bgi[idx] = (n < 384) ? Wf[n * 300 + k] : Wb[(n - 384) * 300 + k];
    }
    if (idx < 768) bias_gi[idx] = (idx < 384) ? bf[idx] : bb[idx - 384];
    if (idx < 512 * 128) {
        int k = idx >> 7, n = idx & 127;
        BW1[idx] = W1[n * 512 + k];
    }
}

// ---------------- embedding mean ----------------
// one wave per sentence; 300 floats = 75 float4 per row
__global__ __launch_bounds__(256) void embed_mean_kernel(
    const int* __restrict__ wids, const float* __restrict__ table,
    float* __restrict__ sent_emb)
{
    int wv = (blockIdx.x << 2) + (threadIdx.x >> 6);
    int lane = threadIdx.x & 63;
    if (wv >= NROWS) return;
    const int* idp = wids + (size_t)wv * Wk;
    float4 a0 = {0,0,0,0}, a1 = {0,0,0,0};
    #pragma unroll 4
    for (int w = 0; w < Wk; ++w) {
        int id = idp[w];
        const float4* r4 = reinterpret_cast<const float4*>(table + (size_t)id * Ek);
        float4 v0 = r4[lane];
        a0.x += v0.x; a0.y += v0.y; a0.z += v0.z; a0.w += v0.w;
        if (lane < 11) {
            float4 v1 = r4[64 + lane];
            a1.x += v1.x; a1.y += v1.y; a1.z += v1.z; a1.w += v1.w;
        }
    }
    const float sc = 1.f / 32.f;
    float4* o4 = reinterpret_cast<float4*>(sent_emb + (size_t)wv * Ek);
    float4 o0 = {a0.x*sc, a0.y*sc, a0.z*sc, a0.w*sc};
    o4[lane] = o0;
    if (lane < 11) {
        float4 o1 = {a1.x*sc, a1.y*sc, a1.z*sc, a1.w*sc};
        o4[64 + lane] = o1;
    }
}

// ---------------- generic fp32 tiled GEMM ----------------
// C[M,N] = A[M,K] * B[K,N]; row-major; lda=K, ldb=N, ldc=N. N % 64 == 0, K % 4 == 0.
template<bool BIAS, bool RELU>
__global__ __launch_bounds__(256) void gemm_kernel(
    const float* __restrict__ A, const float* __restrict__ B,
    const float* __restrict__ bias, float* __restrict__ C,
    int M, int N, int K)
{
    __shared__ float As[64][68];   // transposed: As[k][m]
    __shared__ float Bs[64][68];   // Bs[k][n]
    const int tid = threadIdx.x;
    const int m0 = blockIdx.x * 64;
    const int n0 = blockIdx.y * 64;
    const int tx = tid & 15, ty = tid >> 4;
    const int lr = tid >> 2;   // 0..63
    const int lc = tid & 3;    // 0..3
    float acc[4][4] = {};

    for (int k0 = 0; k0 < K; k0 += 64) {
        // stage A (64 rows x 64 k-cols), store transposed
        #pragma unroll
        for (int i = 0; i < 4; ++i) {
            int kk = lc * 4 + i * 16;
            int gm = m0 + lr;
            int gk = k0 + kk;
            float4 v = {0,0,0,0};
            if (gm < M && gk < K)
                v = *reinterpret_cast<const float4*>(A + (size_t)gm * K + gk);
            As[kk+0][lr] = v.x; As[kk+1][lr] = v.y; As[kk+2][lr] = v.z; As[kk+3][lr] = v.w;
        }
        // stage B (64 k-rows x 64 n-cols)
        #pragma unroll
        for (int i = 0; i < 4; ++i) {
            int nn = lc * 4 + i * 16;
            int gk = k0 + lr;
            float4 v = {0,0,0,0};
            if (gk < K)
                v = *reinterpret_cast<const float4*>(B + (size_t)gk * N + n0 + nn);
            *reinterpret_cast<float4*>(&Bs[lr][nn]) = v;
        }
        __syncthreads();
        #pragma unroll 8
        for (int k = 0; k < 64; ++k) {
            float4 av = *reinterpret_cast<const float4*>(&As[k][ty*4]);
            float4 bv = *reinterpret_cast<const float4*>(&Bs[k][tx*4]);
            acc[0][0] += av.x*bv.x; acc[0][1] += av.x*bv.y; acc[0][2] += av.x*bv.z; acc[0][3] += av.x*bv.w;
            acc[1][0] += av.y*bv.x; acc[1][1] += av.y*bv.y; acc[1][2] += av.y*bv.z; acc[1][3] += av.y*bv.w;
            acc[2][0] += av.z*bv.x; acc[2][1] += av.z*bv.y; acc[2][2] += av.z*bv.z; acc[2][3] += av.z*bv.w;
            acc[3][0] += av.w*bv.x; acc[3][1] += av.w*bv.y; acc[3][2] += av.w*bv.z; acc[3][3] += av.w*bv.w;
        }
        __syncthreads();
    }
    #pragma unroll
    for (int r = 0; r < 4; ++r) {
        int row = m0 + ty * 4 + r;
        if (row < M) {
            float4 v = {acc[r][0], acc[r][1], acc[r][2], acc[r][3]};
            if (BIAS) {
                const float* bp = bias + n0 + tx * 4;
                v.x += bp[0]; v.y += bp[1]; v.z += bp[2]; v.w += bp[3];
            }
            if (RELU) {
                v.x = fmaxf(v.x, 0.f); v.y = fmaxf(v.y, 0.f);
                v.z = fmaxf(v.z, 0.f); v.w = fmaxf(v.w, 0.f);
            }
            *reinterpret_cast<float4*>(C + (size_t)row * N + n0 + tx * 4) = v;
        }
    }
}

// ---------------- GRU scan ----------------
// 64 blocks: blockIdx = dir*32 + b. 768 threads: thread t -> gate row t/2, half t&1.
// Whh row halves held in registers; h in LDS.
__global__ __launch_bounds__(768) void gru_scan_kernel(
    const float* __restrict__ gi,       // [8192, 768], col = dir*384 + g
    const float* __restrict__ Whh_f, const float* __restrict__ Whh_b,
    const float* __restrict__ bhh_f, const float* __restrict__ bhh_b,
    float* __restrict__ sent_rep,       // [8192, 256], col = dir*128 + j
    float* __restrict__ hT)             // [2][32][128]
{
    const int blk = blockIdx.x;
    const int dir = blk >> 5;
    const int b   = blk & 31;
    const int t = threadIdx.x;
    const int row  = t >> 1;
    const int half = t & 1;
    const float* Whh = dir ? Whh_b : Whh_f;
    const float* bhh = dir ? bhh_b : bhh_f;
    __shared__ float hsh[128];
    __shared__ float ghb[384];
    float w[64];
    {
        const float* wp = Whh + row * 128 + half * 64;
        #pragma unroll
        for (int i = 0; i < 64; ++i) w[i] = wp[i];
    }
    const float bias = bhh[row];
    if (t < 128) hsh[t] = 0.f;
    __syncthreads();
    for (int step = 0; step < Sk; ++step) {
        const int s = dir ? (Sk - 1 - step) : step;
        // phase 1: gh = Whh @ h
        float a0 = 0.f, a1 = 0.f, a2 = 0.f, a3 = 0.f;
        #pragma unroll
        for (int i = 0; i < 64; i += 4) {
            float4 h4 = *reinterpret_cast<const float4*>(&hsh[half * 64 + i]);
            a0 += w[i+0] * h4.x; a1 += w[i+1] * h4.y;
            a2 += w[i+2] * h4.z; a3 += w[i+3] * h4.w;
        }
        float part = (a0 + a1) + (a2 + a3);
        part += __shfl_xor(part, 1);
        if (half == 0) ghb[row] = part + bias;
        __syncthreads();
        // phase 2: gates + h update
        if (t < 128) {
            const int j = t;
            const float* gib = gi + (size_t)(b * Sk + s) * GI_N + dir * 384;
            float ir = gib[j], iz = gib[128 + j], inn = gib[256 + j];
            float hr = ghb[j], hz = ghb[128 + j], hn = ghb[256 + j];
            float r = fast_sigmoid(ir + hr);
            float z = fast_sigmoid(iz + hz);
            float n = fast_tanh(inn + r * hn);
            float hold = hsh[j];
            float hnew = (1.f - z) * n + z * hold;
            hsh[j] = hnew;
            sent_rep[(size_t)(b * Sk + s) * 256 + dir * 128 + j] = hnew;
        }
        __syncthreads();
    }
    if (t < 128) hT[dir * 4096 + b * 128 + t] = hsh[t];
}

// ---------------- prep: doc_vec + topic_mat ----------------
// dvtm rows: 0..31 doc_vec[b][256], 32..543 topic_mat[(b*16+t)][256]
__device__ __forceinline__ float4 sr_load_guard(const float* sr, int b, int sidx, int j4) {
    if (sidx < 0 || sidx >= Sk) { float4 z = {0,0,0,0}; return z; }
    return reinterpret_cast<const float4*>(sr)[(size_t)(b * Sk + sidx) * 64 + j4];
}
__global__ __launch_bounds__(64) void prep_kernel(
    const int* __restrict__ tse, const float* __restrict__ sent_rep,
    const float* __restrict__ hT, float* __restrict__ dvtm)
{
    const int b = blockIdx.x;
    const int t = blockIdx.y;
    const int j4 = threadIdx.x;   // 0..63 (float4 col)
    if (t == 16) {
        // doc_vec row b (replicates the reference's stack().reshape quirk)
        int dir = b >> 4;
        int bb = 2 * (b & 15) + (j4 >> 5);
        int jj4 = j4 & 31;
        float4 v = reinterpret_cast<const float4*>(hT)[dir * 1024 + bb * 32 + jj4];
        reinterpret_cast<float4*>(dvtm)[b * 64 + j4] = v;
    } else {
        int st = tse[b * 32 + t * 2];
        int en = tse[b * 32 + t * 2 + 1];
        float4 va, vb;
        if (j4 < 32) {  // forward part (cols 0..127)
            va = sr_load_guard(sent_rep, b, en - 1, j4);
            vb = sr_load_guard(sent_rep, b, st - 2, j4);
        } else {        // backward part (cols 128..255)
            va = sr_load_guard(sent_rep, b, st - 1, j4);
            vb = sr_load_guard(sent_rep, b, en, j4);
        }
        float4 v = {va.x - vb.x, va.y - vb.y, va.z - vb.z, va.w - vb.w};
        reinterpret_cast<float4*>(dvtm)[(32 + b * 16 + t) * 64 + j4] = v;
    }
}

// ---------------- scores ----------------
__global__ __launch_bounds__(256) void scores_kernel(
    const float* __restrict__ SW,    // [8192,512]
    const float* __restrict__ dptp,  // [544,512]
    const float* __restrict__ vatt,  // [512]
    const int* __restrict__ tse,
    float* __restrict__ dsc, float* __restrict__ tsc)
{
    int row = (blockIdx.x << 2) + (threadIdx.x >> 6);
    int lane = threadIdx.x & 63;
    if (row >= NROWS) return;
    int b = row >> 8, s = row & 255;
    int ti = 0;
    #pragma unroll
    for (int t = 1; t < 16; ++t) ti += (s >= tse[b * 32 + t * 2] - 1) ? 1 : 0;
    const float4* swr = reinterpret_cast<const float4*>(SW + (size_t)row * 512);
    const float4* dpr = reinterpret_cast<const float4*>(dptp + (size_t)b * 512);
    const float4* tpr = reinterpret_cast<const float4*>(dptp + (size_t)(32 + b * 16 + ti) * 512);
    const float4* vv  = reinterpret_cast<const float4*>(vatt);
    float sd = 0.f, st = 0.f;
    #pragma unroll
    for (int q = 0; q < 2; ++q) {
        int i = lane * 2 + q;
        float4 sw = swr[i], dp = dpr[i], tp = tpr[i], v = vv[i];
        sd += fast_tanh(sw.x + dp.x) * v.x + fast_tanh(sw.y + dp.y) * v.y
            + fast_tanh(sw.z + dp.z) * v.z + fast_tanh(sw.w + dp.w) * v.w;
        st += fast_tanh(sw.x + tp.x) * v.x + fast_tanh(sw.y + tp.y) * v.y
            + fast_tanh(sw.z + tp.z) * v.z + fast_tanh(sw.w + tp.w) * v.w;
    }
    #pragma unroll
    for (int off = 32; off; off >>= 1) {
        sd += __shfl_xor(sd, off);
        st += __shfl_xor(st, off);
    }
    if (lane == 0) { dsc[row] = sd; tsc[row] = st; }
}

// ---------------- softmax over S per b (both arrays, in place -> weights) ----------------
__global__ __launch_bounds__(256) void softmax_kernel(float* __restrict__ dsc, float* __restrict__ tsc)
{
    const int b = blockIdx.x, sidx = threadIdx.x;
    const int lane = sidx & 63, wid = sidx >> 6;
    __shared__ float rd[4], rt[4];
    float d = dsc[b * Sk + sidx];
    float t = tsc[b * Sk + sidx];
    float md = d, mt = t;
    #pragma unroll
    for (int off = 32; off; off >>= 1) {
        md = fmaxf(md, __shfl_xor(md, off));
        mt = fmaxf(mt, __shfl_xor(mt, off));
    }
    if (lane == 0) { rd[wid] = md; rt[wid] = mt; }
    __syncthreads();
    md = fmaxf(fmaxf(rd[0], rd[1]), fmaxf(rd[2], rd[3]));
    mt = fmaxf(fmaxf(rt[0], rt[1]), fmaxf(rt[2], rt[3]));
    float ed = __expf(d - md), et = __expf(t - mt);
    float sd = ed, stt = et;
    #pragma unroll
    for (int off = 32; off; off >>= 1) {
        sd += __shfl_xor(sd, off);
        stt += __shfl_xor(stt, off);
    }
    __syncthreads();
    if (lane == 0) { rd[wid] = sd; rt[wid] = stt; }
    __syncthreads();
    sd = rd[0] + rd[1] + rd[2] + rd[3];
    stt = rt[0] + rt[1] + rt[2] + rt[3];
    dsc[b * Sk + sidx] = ed / sd;
    tsc[b * Sk + sidx] = et / stt;
}

// ---------------- build inp = [sent_rep, context] ----------------
__global__ __launch_bounds__(128) void build_inp_kernel(
    const float* __restrict__ sent_rep, const float* __restrict__ dvtm,
    const float* __restrict__ dw, const float* __restrict__ tw,
    const int* __restrict__ tse, float* __restrict__ inp)
{
    int row = blockIdx.x;
    int b = row >> 8, s = row & 255;
    int f4c = threadIdx.x;   // 0..127
    float4 v;
    if (f4c < 64) {
        v = reinterpret_cast<const float4*>(sent_rep)[(size_t)row * 64 + f4c];
    } else {
        int ti = 0;
        #pragma unroll
        for (int t = 1; t < 16; ++t) ti += (s >= tse[b * 32 + t * 2] - 1) ? 1 : 0;
        float dwv = dw[row], twv = tw[row];
        int j4 = f4c - 64;
        float4 dv = reinterpret_cast<const float4*>(dvtm)[b * 64 + j4];
        float4 tm = reinterpret_cast<const float4*>(dvtm)[(32 + b * 16 + ti) * 64 + j4];
        v.x = dwv * dv.x + twv * tm.x;
        v.y = dwv * dv.y + twv * tm.y;
        v.z = dwv * dv.z + twv * tm.z;
        v.w = dwv * dv.w + twv * tm.w;
    }
    reinterpret_cast<float4*>(inp)[(size_t)row * 128 + f4c] = v;
}

// ---------------- final logits ----------------
__global__ __launch_bounds__(256) void logits_kernel(
    const float* __restrict__ hdd, const float* __restrict__ W2,
    const float* __restrict__ b2, float* __restrict__ out)
{
    int row = (blockIdx.x << 2) + (threadIdx.x >> 6);
    int lane = threadIdx.x & 63;
    if (row >= NROWS) return;
    float acc = hdd[(size_t)row * 128 + lane] * W2[lane]
              + hdd[(size_t)row * 128 + 64 + lane] * W2[64 + lane];
    #pragma unroll
    for (int off = 32; off; off >>= 1) acc += __shfl_xor(acc, off);
    if (lane == 0) out[row] = acc + b2[0];
}

// ---------------- launch ----------------
extern "C" void kernel_launch(void* const* d_in, const int* in_sizes, int n_in,
                              void* d_out, int out_size, void* d_ws, size_t ws_size,
                              hipStream_t stream)
{
    const int*   wids  = (const int*)d_in[0];
    const int*   tse   = (const int*)d_in[1];
    const float* table = (const float*)d_in[2];
    const float* Wihf  = (const float*)d_in[3];
    const float* Whhf  = (const float*)d_in[4];
    const float* bihf  = (const float*)d_in[5];
    const float* bhhf  = (const float*)d_in[6];
    const float* Wihb  = (const float*)d_in[7];
    const float* Whhb  = (const float*)d_in[8];
    const float* bihb  = (const float*)d_in[9];
    const float* bhhb  = (const float*)d_in[10];
    const float* vatt  = (const float*)d_in[11];
    const float* Watt  = (const float*)d_in[12];
    const float* W1    = (const float*)d_in[13];
    const float* b1    = (const float*)d_in[14];
    const float* W2    = (const float*)d_in[15];
    const float* b2    = (const float*)d_in[16];
    float* ws = (float*)d_ws;
    float* out = (float*)d_out;

    // workspace layout (float offsets)
    float* sent_emb = ws + 0;          // 2,457,600  (dead after gi GEMM)
    float* gi       = ws + 2457600;    // 6,291,456  (dead after scan)
    float* sent_rep = ws + 8749056;    // 2,097,152
    float* hT       = ws + 10846208;   // 8,192
    float* dvtm     = ws + 10854400;   // 139,264 ([544][256])
    float* dptp     = ws + 10993664;   // 278,528 ([544][512])
    float* dsc      = ws + 11272192;   // 8,192
    float* tsc      = ws + 11280384;   // 8,192
    float* Bgi      = ws + 11288576;   // 230,400
    float* bias_gi  = ws + 11518976;   // 768
    float* BW1      = ws + 11519744;   // 65,536  -> end 11,585,280 floats
    // reuse dead regions:
    float* SW       = ws + 0;          // [8192][512] over sent_emb+gi (dead)
    float* inp      = ws + 4194304;    // [8192][512]
    float* hdd      = ws + 0;          // [8192][128] over SW (dead after scores)

    if (ws_size < (size_t)11585280 * sizeof(float)) return;

    pack_kernel<<<900, 256, 0, stream>>>(Wihf, Wihb, bihf, bihb, W1, Bgi, bias_gi, BW1);
    embed_mean_kernel<<<2048, 256, 0, stream>>>(wids, table, sent_emb);
    gemm_kernel<true,false><<<dim3(128, 12), 256, 0, stream>>>(sent_emb, Bgi, bias_gi, gi, NROWS, 768, 300);
    gru_scan_kernel<<<64, 768, 0, stream>>>(gi, Whhf, Whhb, bhhf, bhhb, sent_rep, hT);
    prep_kernel<<<dim3(32, 17), 64, 0, stream>>>(tse, sent_rep, hT, dvtm);
    gemm_kernel<false,false><<<dim3(128, 8), 256, 0, stream>>>(sent_rep, Watt + 256 * 512, nullptr, SW, NROWS, 512, 256);
    gemm_kernel<false,false><<<dim3(9, 8), 256, 0, stream>>>(dvtm, Watt, nullptr, dptp, 544, 512, 256);
    scores_kernel<<<2048, 256, 0, stream>>>(SW, dptp, vatt, tse, dsc, tsc);
    softmax_kernel<<<32, 256, 0, stream>>>(dsc, tsc);
    build_inp_kernel<<<NROWS, 128, 0, stream>>>(sent_rep, dvtm, dsc, tsc, tse, inp);
    gemm_kernel<true,true><<<dim3(128, 2), 256, 0, stream>>>(inp, BW1, b1, hdd, NROWS, 128, 512);
    logits_kernel<<<2048, 256, 0, stream>>>(hdd, W2, b2, out);
}

// Round 2
// 404.411 us; speedup vs baseline: 1.2971x; 1.2971x over previous
//
#include <hip/hip_runtime.h>
#include <hip/hip_bf16.h>
#include <cstdint>

// Problem constants
#define Bk 32
#define Sk 256
#define Wk 32
#define Tk 16
#define Ek 300
#define Hk 128
#define Dk 128
#define NROWS (Bk*Sk)          // 8192
#define GI_N  (3*Hk*2)         // 768

// ---------------- helpers ----------------
__device__ __forceinline__ float fast_sigmoid(float x) {
    return 1.f / (1.f + __expf(-x));
}
__device__ __forceinline__ float fast_tanh(float x) {
    float ax = fabsf(x);
    float e = __expf(2.f * ax);
    float t = 1.f - 2.f / (1.f + e);
    return copysignf(t, x);
}

// ---------------- pack kernel ----------------
__global__ __launch_bounds__(256) void pack_kernel(
    const float* __restrict__ Wf, const float* __restrict__ Wb,
    const float* __restrict__ bf, const float* __restrict__ bb,
    const float* __restrict__ W1,
    float* __restrict__ Bgi, float* __restrict__ bias_gi, float* __restrict__ BW1)
{
    int idx = blockIdx.x * 256 + threadIdx.x;
    if (idx < 300 * 768) {
        int k = idx / 768, n = idx % 768;
        Bgi[idx] = (n < 384) ? Wf[n * 300 + k] : Wb[(n - 384) * 300 + k];
    }
    if (idx < 768) bias_gi[idx] = (idx < 384) ? bf[idx] : bb[idx - 384];
    if (idx < 512 * 128) {
        int k = idx >> 7, n = idx & 127;
        BW1[idx] = W1[n * 512 + k];
    }
}

// ---------------- embedding mean ----------------
__global__ __launch_bounds__(256) void embed_mean_kernel(
    const int* __restrict__ wids, const float* __restrict__ table,
    float* __restrict__ sent_emb)
{
    int wv = (blockIdx.x << 2) + (threadIdx.x >> 6);
    int lane = threadIdx.x & 63;
    if (wv >= NROWS) return;
    const int* idp = wids + (size_t)wv * Wk;
    float4 a0 = {0,0,0,0}, a1 = {0,0,0,0};
    #pragma unroll 4
    for (int w = 0; w < Wk; ++w) {
        int id = idp[w];
        const float4* r4 = reinterpret_cast<const float4*>(table + (size_t)id * Ek);
        float4 v0 = r4[lane];
        a0.x += v0.x; a0.y += v0.y; a0.z += v0.z; a0.w += v0.w;
        if (lane < 11) {
            float4 v1 = r4[64 + lane];
            a1.x += v1.x; a1.y += v1.y; a1.z += v1.z; a1.w += v1.w;
        }
    }
    const float sc = 1.f / 32.f;
    float4* o4 = reinterpret_cast<float4*>(sent_emb + (size_t)wv * Ek);
    float4 o0 = {a0.x*sc, a0.y*sc, a0.z*sc, a0.w*sc};
    o4[lane] = o0;
    if (lane < 11) {
        float4 o1 = {a1.x*sc, a1.y*sc, a1.z*sc, a1.w*sc};
        o4[64 + lane] = o1;
    }
}

// ---------------- generic fp32 tiled GEMM ----------------
template<bool BIAS, bool RELU>
__global__ __launch_bounds__(256) void gemm_kernel(
    const float* __restrict__ A, const float* __restrict__ B,
    const float* __restrict__ bias, float* __restrict__ C,
    int M, int N, int K)
{
    __shared__ float As[64][68];   // transposed: As[k][m]
    __shared__ float Bs[64][68];   // Bs[k][n]
    const int tid = threadIdx.x;
    const int m0 = blockIdx.x * 64;
    const int n0 = blockIdx.y * 64;
    const int tx = tid & 15, ty = tid >> 4;
    const int lr = tid >> 2;   // 0..63
    const int lc = tid & 3;    // 0..3
    float acc[4][4] = {};

    for (int k0 = 0; k0 < K; k0 += 64) {
        #pragma unroll
        for (int i = 0; i < 4; ++i) {
            int kk = lc * 4 + i * 16;
            int gm = m0 + lr;
            int gk = k0 + kk;
            float4 v = {0,0,0,0};
            if (gm < M && gk < K)
                v = *reinterpret_cast<const float4*>(A + (size_t)gm * K + gk);
            As[kk+0][lr] = v.x; As[kk+1][lr] = v.y; As[kk+2][lr] = v.z; As[kk+3][lr] = v.w;
        }
        #pragma unroll
        for (int i = 0; i < 4; ++i) {
            int nn = lc * 4 + i * 16;
            int gk = k0 + lr;
            float4 v = {0,0,0,0};
            if (gk < K)
                v = *reinterpret_cast<const float4*>(B + (size_t)gk * N + n0 + nn);
            *reinterpret_cast<float4*>(&Bs[lr][nn]) = v;
        }
        __syncthreads();
        #pragma unroll 8
        for (int k = 0; k < 64; ++k) {
            float4 av = *reinterpret_cast<const float4*>(&As[k][ty*4]);
            float4 bv = *reinterpret_cast<const float4*>(&Bs[k][tx*4]);
            acc[0][0] += av.x*bv.x; acc[0][1] += av.x*bv.y; acc[0][2] += av.x*bv.z; acc[0][3] += av.x*bv.w;
            acc[1][0] += av.y*bv.x; acc[1][1] += av.y*bv.y; acc[1][2] += av.y*bv.z; acc[1][3] += av.y*bv.w;
            acc[2][0] += av.z*bv.x; acc[2][1] += av.z*bv.y; acc[2][2] += av.z*bv.z; acc[2][3] += av.z*bv.w;
            acc[3][0] += av.w*bv.x; acc[3][1] += av.w*bv.y; acc[3][2] += av.w*bv.z; acc[3][3] += av.w*bv.w;
        }
        __syncthreads();
    }
    #pragma unroll
    for (int r = 0; r < 4; ++r) {
        int row = m0 + ty * 4 + r;
        if (row < M) {
            float4 v = {acc[r][0], acc[r][1], acc[r][2], acc[r][3]};
            if (BIAS) {
                const float* bp = bias + n0 + tx * 4;
                v.x += bp[0]; v.y += bp[1]; v.z += bp[2]; v.w += bp[3];
            }
            if (RELU) {
                v.x = fmaxf(v.x, 0.f); v.y = fmaxf(v.y, 0.f);
                v.z = fmaxf(v.z, 0.f); v.w = fmaxf(v.w, 0.f);
            }
            *reinterpret_cast<float4*>(C + (size_t)row * N + n0 + tx * 4) = v;
        }
    }
}

// ---------------- GRU scan ----------------
// 64 blocks: blockIdx = dir*32 + b. 768 threads: thread t -> gate row t/2, half t&1.
// Whh row halves held in 16 NAMED float4 registers (r1: compiler demoted the
// w[64] array -> VGPR_Count=48 and per-step L2 re-fetch of Whh; named scalars
// stay resident). h in LDS with +8 float pad between halves so the per-inst
// 2-address broadcast read hits disjoint banks. gi prefetched one step ahead.
__global__ __launch_bounds__(768, 1) void gru_scan_kernel(
    const float* __restrict__ gi,       // [8192, 768], col = dir*384 + g
    const float* __restrict__ Whh_f, const float* __restrict__ Whh_b,
    const float* __restrict__ bhh_f, const float* __restrict__ bhh_b,
    float* __restrict__ sent_rep,       // [8192, 256], col = dir*128 + j
    float* __restrict__ hT)             // [2][32][128]
{
    const int blk = blockIdx.x;
    const int dir = blk >> 5;
    const int b   = blk & 31;
    const int t = threadIdx.x;
    const int row  = t >> 1;
    const int half = t & 1;
    const float* Whh = dir ? Whh_b : Whh_f;
    const float* bhh = dir ? bhh_b : bhh_f;
    __shared__ float hsh[136];   // h[j] at j + (j>=64 ? 8 : 0)
    __shared__ float ghb[384];

    const float4* wp4 = reinterpret_cast<const float4*>(Whh + row * 128 + half * 64);
    float4 w0  = wp4[0],  w1  = wp4[1],  w2  = wp4[2],  w3  = wp4[3];
    float4 w4  = wp4[4],  w5  = wp4[5],  w6  = wp4[6],  w7  = wp4[7];
    float4 w8  = wp4[8],  w9  = wp4[9],  w10 = wp4[10], w11 = wp4[11];
    float4 w12 = wp4[12], w13 = wp4[13], w14 = wp4[14], w15 = wp4[15];
    const float bias = bhh[row];

    if (t < 136) hsh[t] = 0.f;

    // prefetch gi for first step
    float gir = 0.f, giz = 0.f, gin_ = 0.f;
    if (t < 128) {
        const int s0 = dir ? (Sk - 1) : 0;
        const float* g0 = gi + (size_t)(b * Sk + s0) * GI_N + dir * 384 + t;
        gir = g0[0]; giz = g0[128]; gin_ = g0[256];
    }
    __syncthreads();

    const float* hb = &hsh[half * 72];   // half 0 -> idx 0, half 1 -> idx 72
    for (int step = 0; step < Sk; ++step) {
        const int s = dir ? (Sk - 1 - step) : step;
        // phase 1: gh = Whh @ h  (all 768 threads)
        float a0 = 0.f, a1 = 0.f, a2 = 0.f, a3 = 0.f;
        #define MAC4(q, wq) { float4 h4 = *reinterpret_cast<const float4*>(hb + 4*(q)); \
            a0 = fmaf(wq.x, h4.x, a0); a1 = fmaf(wq.y, h4.y, a1); \
            a2 = fmaf(wq.z, h4.z, a2); a3 = fmaf(wq.w, h4.w, a3); }
        MAC4(0,w0)  MAC4(1,w1)  MAC4(2,w2)  MAC4(3,w3)
        MAC4(4,w4)  MAC4(5,w5)  MAC4(6,w6)  MAC4(7,w7)
        MAC4(8,w8)  MAC4(9,w9)  MAC4(10,w10) MAC4(11,w11)
        MAC4(12,w12) MAC4(13,w13) MAC4(14,w14) MAC4(15,w15)
        #undef MAC4
        float part = (a0 + a1) + (a2 + a3);
        part += __shfl_xor(part, 1);
        if (half == 0) ghb[row] = part + bias;
        __syncthreads();
        // phase 2: gates + h update (threads 0..127)
        if (t < 128) {
            const int j = t;
            float hr = ghb[j], hz = ghb[128 + j], hn = ghb[256 + j];
            float r = fast_sigmoid(gir + hr);
            float z = fast_sigmoid(giz + hz);
            float n = fast_tanh(gin_ + r * hn);
            const int ji = j + ((j >> 6) << 3);   // padded index
            float hold = hsh[ji];
            float hnew = (1.f - z) * n + z * hold;
            hsh[ji] = hnew;
            sent_rep[(size_t)(b * Sk + s) * 256 + dir * 128 + j] = hnew;
            // prefetch next step's gi
            if (step < Sk - 1) {
                const int sn = dir ? (s - 1) : (s + 1);
                const float* g = gi + (size_t)(b * Sk + sn) * GI_N + dir * 384 + j;
                gir = g[0]; giz = g[128]; gin_ = g[256];
            }
        }
        __syncthreads();
    }
    if (t < 128) {
        const int ji = t + ((t >> 6) << 3);
        hT[dir * 4096 + b * 128 + t] = hsh[ji];
    }
}

// ---------------- prep: doc_vec + topic_mat ----------------
__device__ __forceinline__ float4 sr_load_guard(const float* sr, int b, int sidx, int j4) {
    if (sidx < 0 || sidx >= Sk) { float4 z = {0,0,0,0}; return z; }
    return reinterpret_cast<const float4*>(sr)[(size_t)(b * Sk + sidx) * 64 + j4];
}
__global__ __launch_bounds__(64) void prep_kernel(
    const int* __restrict__ tse, const float* __restrict__ sent_rep,
    const float* __restrict__ hT, float* __restrict__ dvtm)
{
    const int b = blockIdx.x;
    const int t = blockIdx.y;
    const int j4 = threadIdx.x;   // 0..63 (float4 col)
    if (t == 16) {
        int dir = b >> 4;
        int bb = 2 * (b & 15) + (j4 >> 5);
        int jj4 = j4 & 31;
        float4 v = reinterpret_cast<const float4*>(hT)[dir * 1024 + bb * 32 + jj4];
        reinterpret_cast<float4*>(dvtm)[b * 64 + j4] = v;
    } else {
        int st = tse[b * 32 + t * 2];
        int en = tse[b * 32 + t * 2 + 1];
        float4 va, vb;
        if (j4 < 32) {
            va = sr_load_guard(sent_rep, b, en - 1, j4);
            vb = sr_load_guard(sent_rep, b, st - 2, j4);
        } else {
            va = sr_load_guard(sent_rep, b, st - 1, j4);
            vb = sr_load_guard(sent_rep, b, en, j4);
        }
        float4 v = {va.x - vb.x, va.y - vb.y, va.z - vb.z, va.w - vb.w};
        reinterpret_cast<float4*>(dvtm)[(32 + b * 16 + t) * 64 + j4] = v;
    }
}

// ---------------- scores ----------------
__global__ __launch_bounds__(256) void scores_kernel(
    const float* __restrict__ SW,    // [8192,512]
    const float* __restrict__ dptp,  // [544,512]
    const float* __restrict__ vatt,  // [512]
    const int* __restrict__ tse,
    float* __restrict__ dsc, float* __restrict__ tsc)
{
    int row = (blockIdx.x << 2) + (threadIdx.x >> 6);
    int lane = threadIdx.x & 63;
    if (row >= NROWS) return;
    int b = row >> 8, s = row & 255;
    int ti = 0;
    #pragma unroll
    for (int t = 1; t < 16; ++t) ti += (s >= tse[b * 32 + t * 2] - 1) ? 1 : 0;
    const float4* swr = reinterpret_cast<const float4*>(SW + (size_t)row * 512);
    const float4* dpr = reinterpret_cast<const float4*>(dptp + (size_t)b * 512);
    const float4* tpr = reinterpret_cast<const float4*>(dptp + (size_t)(32 + b * 16 + ti) * 512);
    const float4* vv  = reinterpret_cast<const float4*>(vatt);
    float sd = 0.f, st = 0.f;
    #pragma unroll
    for (int q = 0; q < 2; ++q) {
        int i = lane * 2 + q;
        float4 sw = swr[i], dp = dpr[i], tp = tpr[i], v = vv[i];
        sd += fast_tanh(sw.x + dp.x) * v.x + fast_tanh(sw.y + dp.y) * v.y
            + fast_tanh(sw.z + dp.z) * v.z + fast_tanh(sw.w + dp.w) * v.w;
        st += fast_tanh(sw.x + tp.x) * v.x + fast_tanh(sw.y + tp.y) * v.y
            + fast_tanh(sw.z + tp.z) * v.z + fast_tanh(sw.w + tp.w) * v.w;
    }
    #pragma unroll
    for (int off = 32; off; off >>= 1) {
        sd += __shfl_xor(sd, off);
        st += __shfl_xor(st, off);
    }
    if (lane == 0) { dsc[row] = sd; tsc[row] = st; }
}

// ---------------- softmax ----------------
__global__ __launch_bounds__(256) void softmax_kernel(float* __restrict__ dsc, float* __restrict__ tsc)
{
    const int b = blockIdx.x, sidx = threadIdx.x;
    const int lane = sidx & 63, wid = sidx >> 6;
    __shared__ float rd[4], rt[4];
    float d = dsc[b * Sk + sidx];
    float t = tsc[b * Sk + sidx];
    float md = d, mt = t;
    #pragma unroll
    for (int off = 32; off; off >>= 1) {
        md = fmaxf(md, __shfl_xor(md, off));
        mt = fmaxf(mt, __shfl_xor(mt, off));
    }
    if (lane == 0) { rd[wid] = md; rt[wid] = mt; }
    __syncthreads();
    md = fmaxf(fmaxf(rd[0], rd[1]), fmaxf(rd[2], rd[3]));
    mt = fmaxf(fmaxf(rt[0], rt[1]), fmaxf(rt[2], rt[3]));
    float ed = __expf(d - md), et = __expf(t - mt);
    float sd = ed, stt = et;
    #pragma unroll
    for (int off = 32; off; off >>= 1) {
        sd += __shfl_xor(sd, off);
        stt += __shfl_xor(stt, off);
    }
    __syncthreads();
    if (lane == 0) { rd[wid] = sd; rt[wid] = stt; }
    __syncthreads();
    sd = rd[0] + rd[1] + rd[2] + rd[3];
    stt = rt[0] + rt[1] + rt[2] + rt[3];
    dsc[b * Sk + sidx] = ed / sd;
    tsc[b * Sk + sidx] = et / stt;
}

// ---------------- build inp = [sent_rep, context] ----------------
__global__ __launch_bounds__(128) void build_inp_kernel(
    const float* __restrict__ sent_rep, const float* __restrict__ dvtm,
    const float* __restrict__ dw, const float* __restrict__ tw,
    const int* __restrict__ tse, float* __restrict__ inp)
{
    int row = blockIdx.x;
    int b = row >> 8, s = row & 255;
    int f4c = threadIdx.x;   // 0..127
    float4 v;
    if (f4c < 64) {
        v = reinterpret_cast<const float4*>(sent_rep)[(size_t)row * 64 + f4c];
    } else {
        int ti = 0;
        #pragma unroll
        for (int t = 1; t < 16; ++t) ti += (s >= tse[b * 32 + t * 2] - 1) ? 1 : 0;
        float dwv = dw[row], twv = tw[row];
        int j4 = f4c - 64;
        float4 dv = reinterpret_cast<const float4*>(dvtm)[b * 64 + j4];
        float4 tm = reinterpret_cast<const float4*>(dvtm)[(32 + b * 16 + ti) * 64 + j4];
        v.x = dwv * dv.x + twv * tm.x;
        v.y = dwv * dv.y + twv * tm.y;
        v.z = dwv * dv.z + twv * tm.z;
        v.w = dwv * dv.w + twv * tm.w;
    }
    reinterpret_cast<float4*>(inp)[(size_t)row * 128 + f4c] = v;
}

// ---------------- final logits ----------------
__global__ __launch_bounds__(256) void logits_kernel(
    const float* __restrict__ hdd, const float* __restrict__ W2,
    const float* __restrict__ b2, float* __restrict__ out)
{
    int row = (blockIdx.x << 2) + (threadIdx.x >> 6);
    int lane = threadIdx.x & 63;
    if (row >= NROWS) return;
    float acc = hdd[(size_t)row * 128 + lane] * W2[lane]
              + hdd[(size_t)row * 128 + 64 + lane] * W2[64 + lane];
    #pragma unroll
    for (int off = 32; off; off >>= 1) acc += __shfl_xor(acc, off);
    if (lane == 0) out[row] = acc + b2[0];
}

// ---------------- launch ----------------
extern "C" void kernel_launch(void* const* d_in, const int* in_sizes, int n_in,
                              void* d_out, int out_size, void* d_ws, size_t ws_size,
                              hipStream_t stream)
{
    const int*   wids  = (const int*)d_in[0];
    const int*   tse   = (const int*)d_in[1];
    const float* table = (const float*)d_in[2];
    const float* Wihf  = (const float*)d_in[3];
    const float* Whhf  = (const float*)d_in[4];
    const float* bihf  = (const float*)d_in[5];
    const float* bhhf  = (const float*)d_in[6];
    const float* Wihb  = (const float*)d_in[7];
    const float* Whhb  = (const float*)d_in[8];
    const float* bihb  = (const float*)d_in[9];
    const float* bhhb  = (const float*)d_in[10];
    const float* vatt  = (const float*)d_in[11];
    const float* Watt  = (const float*)d_in[12];
    const float* W1    = (const float*)d_in[13];
    const float* b1    = (const float*)d_in[14];
    const float* W2    = (const float*)d_in[15];
    const float* b2    = (const float*)d_in[16];
    float* ws = (float*)d_ws;
    float* out = (float*)d_out;

    float* sent_emb = ws + 0;          // 2,457,600  (dead after gi GEMM)
    float* gi       = ws + 2457600;    // 6,291,456  (dead after scan)
    float* sent_rep = ws + 8749056;    // 2,097,152
    float* hT       = ws + 10846208;   // 8,192
    float* dvtm     = ws + 10854400;   // 139,264 ([544][256])
    float* dptp     = ws + 10993664;   // 278,528 ([544][512])
    float* dsc      = ws + 11272192;   // 8,192
    float* tsc      = ws + 11280384;   // 8,192
    float* Bgi      = ws + 11288576;   // 230,400
    float* bias_gi  = ws + 11518976;   // 768
    float* BW1      = ws + 11519744;   // 65,536  -> end 11,585,280 floats
    float* SW       = ws + 0;          // [8192][512] over sent_emb+gi (dead)
    float* inp      = ws + 4194304;    // [8192][512]
    float* hdd      = ws + 0;          // [8192][128] over SW (dead after scores)

    if (ws_size < (size_t)11585280 * sizeof(float)) return;

    pack_kernel<<<900, 256, 0, stream>>>(Wihf, Wihb, bihf, bihb, W1, Bgi, bias_gi, BW1);
    embed_mean_kernel<<<2048, 256, 0, stream>>>(wids, table, sent_emb);
    gemm_kernel<true,false><<<dim3(128, 12), 256, 0, stream>>>(sent_emb, Bgi, bias_gi, gi, NROWS, 768, 300);
    gru_scan_kernel<<<64, 768, 0, stream>>>(gi, Whhf, Whhb, bhhf, bhhb, sent_rep, hT);
    prep_kernel<<<dim3(32, 17), 64, 0, stream>>>(tse, sent_rep, hT, dvtm);
    gemm_kernel<false,false><<<dim3(128, 8), 256, 0, stream>>>(sent_rep, Watt + 256 * 512, nullptr, SW, NROWS, 512, 256);
    gemm_kernel<false,false><<<dim3(9, 8), 256, 0, stream>>>(dvtm, Watt, nullptr, dptp, 544, 512, 256);
    scores_kernel<<<2048, 256, 0, stream>>>(SW, dptp, vatt, tse, dsc, tsc);
    softmax_kernel<<<32, 256, 0, stream>>>(dsc, tsc);
    build_inp_kernel<<<NROWS, 128, 0, stream>>>(sent_rep, dvtm, dsc, tsc, tse, inp);
    gemm_kernel<true,true><<<dim3(128, 2), 256, 0, stream>>>(inp, BW1, b1, hdd, NROWS, 128, 512);
    logits_kernel<<<2048, 256, 0, stream>>>(hdd, W2, b2, out);
}